// Round 5
// baseline (411.412 us; speedup 1.0000x reference)
//
#include <hip/hip_runtime.h>
#include <math.h>
#include <float.h>

#define NN 8192

typedef __bf16 bf16x8 __attribute__((ext_vector_type(8)));
typedef __bf16 bf16x4 __attribute__((ext_vector_type(4)));
typedef float f32x4 __attribute__((ext_vector_type(4)));

constexpr float POS_R2 = 0.0375f * 0.0375f;
constexpr float NEG_R2 = 0.1f * 0.1f;
constexpr float EPSF = 1e-7f;
constexpr float PRC = POS_R2 - EPSF;  // pos:  d2p < PRC
constexpr float NRC = NEG_R2 - EPSF;  // neg:  d2p > NRC
constexpr float POS_TH = 0.1f;
constexpr float NEG_TH = 1.4f;

// ws byte offsets
#define FT_OFF 0                            // bf16 [NN][32] tgt feats (64 B/row)
#define FS2_OFF (NN * 64)                   // bf16 [NN][32] -2 * src feats
#define PSX_OFF (2 * NN * 64)               // bf16 [NN][16] src pos ext (32 B/row)
#define PTX_OFF (2 * NN * 64 + NN * 32)     // bf16 [NN][16] tgt pos ext
#define PAD_OFF (2 * NN * 64 + 2 * NN * 32) // 64 B zeros (quad 2/3 over-read)
#define FNS_OFF (PAD_OFF + 64)              // f32 [NN] src feat |.|^2
#define NT_OFF (FNS_OFF + NN * 4)           // f32 [16][16][32] tgt norms, transposed
#define MAXB_OFF (NT_OFF + NN * 4)
#define MINB_OFF (MAXB_OFF + NN * 4)

// ---------------------------------------------------------------------------
// Phase 1: gather + transform + bf16 conversion + MFMA operand packing.
// 8 threads per correspondence; part p handles feat float4 chunk p.
// ---------------------------------------------------------------------------
__global__ __launch_bounds__(256) void hcl_prep(
    const float* __restrict__ src_pcd, const float* __restrict__ tgt_pcd,
    const float* __restrict__ src_feats, const float* __restrict__ tgt_feats,
    const int* __restrict__ corr, const float* __restrict__ rot,
    const float* __restrict__ trans, char* __restrict__ ws) {
  int t = blockIdx.x * 256 + threadIdx.x;  // 0..65535
  int i = t >> 3;
  int p = t & 7;
  int ci = corr[2 * i];
  int cj = corr[2 * i + 1];

  // ---- feats: chunk p (4 dims) ----
  float4 a = ((const float4*)(src_feats + (size_t)ci * 32))[p];
  float4 b = ((const float4*)(tgt_feats + (size_t)cj * 32))[p];
  __bf16 h0 = (__bf16)a.x, h1 = (__bf16)a.y, h2 = (__bf16)a.z, h3 = (__bf16)a.w;
  float f0 = (float)h0, f1 = (float)h1, f2 = (float)h2, f3 = (float)h3;
  float na = f0 * f0 + f1 * f1 + f2 * f2 + f3 * f3;
  bf16x4 osrc;
  osrc[0] = (__bf16)(-2.f * f0); osrc[1] = (__bf16)(-2.f * f1);
  osrc[2] = (__bf16)(-2.f * f2); osrc[3] = (__bf16)(-2.f * f3);
  __bf16 g0 = (__bf16)b.x, g1 = (__bf16)b.y, g2 = (__bf16)b.z, g3 = (__bf16)b.w;
  float e0 = (float)g0, e1 = (float)g1, e2 = (float)g2, e3 = (float)g3;
  float nb = e0 * e0 + e1 * e1 + e2 * e2 + e3 * e3;
  bf16x4 otgt;
  otgt[0] = g0; otgt[1] = g1; otgt[2] = g2; otgt[3] = g3;
  *(bf16x4*)(ws + FS2_OFF + (size_t)i * 64 + p * 8) = osrc;
  *(bf16x4*)(ws + FT_OFF + (size_t)i * 64 + p * 8) = otgt;

  // norm reduce across the 8 parts (adjacent lanes)
  na += __shfl_xor(na, 1, 8);
  na += __shfl_xor(na, 2, 8);
  na += __shfl_xor(na, 4, 8);
  nb += __shfl_xor(nb, 1, 8);
  nb += __shfl_xor(nb, 2, 8);
  nb += __shfl_xor(nb, 4, 8);

  __bf16 one = (__bf16)1.0f, zero = (__bf16)0.0f;

  if (p == 0) {
    ((float*)(ws + FNS_OFF))[i] = na;
    // transposed tgt-norm: NT[chunk=i>>9][n=i&15][s=(i>>4)&31]
    int nt_idx = ((i >> 9) << 9) + (i & 15) * 32 + ((i >> 4) & 31);
    ((float*)(ws + NT_OFF))[nt_idx] = nb;
    ((unsigned int*)(ws + MAXB_OFF))[i] = 0u;           // max(d2f) sentinel
    ((unsigned int*)(ws + MINB_OFF))[i] = 0x7F7FFFFFu;  // FLT_MAX bits
  } else if (p == 3) {
    if (i == 0) {  // zero the over-read pad after PTX
      f32x4 z = {0.f, 0.f, 0.f, 0.f};
      ((f32x4*)(ws + PAD_OFF))[0] = z;
      ((f32x4*)(ws + PAD_OFF))[1] = z;
      ((f32x4*)(ws + PAD_OFF))[2] = z;
      ((f32x4*)(ws + PAD_OFF))[3] = z;
    }
  } else if (p == 1) {
    // src pos-ext (16 slots): [ah(3), ah(3), al(3), sah, sal, 1, 1, 0,0,0]
    float r00 = rot[0], r01 = rot[1], r02 = rot[2];
    float r10 = rot[3], r11 = rot[4], r12 = rot[5];
    float r20 = rot[6], r21 = rot[7], r22 = rot[8];
    float t0 = trans[0], t1 = trans[1], t2 = trans[2];
    float px = src_pcd[ci * 3 + 0], py = src_pcd[ci * 3 + 1], pz = src_pcd[ci * 3 + 2];
    float qx = r00 * px + r01 * py + r02 * pz + t0;
    float qy = r10 * px + r11 * py + r12 * pz + t1;
    float qz = r20 * px + r21 * py + r22 * pz + t2;
    float sa = qx * qx + qy * qy + qz * qz;
    __bf16 qhx = (__bf16)qx, qhy = (__bf16)qy, qhz = (__bf16)qz;
    __bf16 qlx = (__bf16)(qx - (float)qhx);
    __bf16 qly = (__bf16)(qy - (float)qhy);
    __bf16 qlz = (__bf16)(qz - (float)qhz);
    __bf16 sah = (__bf16)sa;
    __bf16 sal = (__bf16)(sa - (float)sah);
    bf16x8 v0, v1;
    v0[0] = qhx; v0[1] = qhy; v0[2] = qhz; v0[3] = qhx; v0[4] = qhy; v0[5] = qhz;
    v0[6] = qlx; v0[7] = qly;
    v1[0] = qlz; v1[1] = sah; v1[2] = sal; v1[3] = one; v1[4] = one;
    v1[5] = zero; v1[6] = zero; v1[7] = zero;
    bf16x8* o = (bf16x8*)(ws + PSX_OFF + (size_t)i * 32);
    o[0] = v0;
    o[1] = v1;
  } else if (p == 2) {
    // tgt pos-ext (16 slots): [-2bh(3), -2bl(3), -2bh(3), 1, 1, sbh, sbl, 0,0,0]
    float ux = tgt_pcd[cj * 3 + 0], uy = tgt_pcd[cj * 3 + 1], uz = tgt_pcd[cj * 3 + 2];
    float sb = ux * ux + uy * uy + uz * uz;
    __bf16 uhx = (__bf16)ux, uhy = (__bf16)uy, uhz = (__bf16)uz;
    __bf16 ulx = (__bf16)(ux - (float)uhx);
    __bf16 uly = (__bf16)(uy - (float)uhy);
    __bf16 ulz = (__bf16)(uz - (float)uhz);
    __bf16 sbh = (__bf16)sb;
    __bf16 sbl = (__bf16)(sb - (float)sbh);
    __bf16 m2hx = (__bf16)(-2.f * (float)uhx), m2hy = (__bf16)(-2.f * (float)uhy),
           m2hz = (__bf16)(-2.f * (float)uhz);
    __bf16 m2lx = (__bf16)(-2.f * (float)ulx), m2ly = (__bf16)(-2.f * (float)uly),
           m2lz = (__bf16)(-2.f * (float)ulz);
    bf16x8 w0, w1;
    w0[0] = m2hx; w0[1] = m2hy; w0[2] = m2hz; w0[3] = m2lx; w0[4] = m2ly; w0[5] = m2lz;
    w0[6] = m2hx; w0[7] = m2hy;
    w1[0] = m2hz; w1[1] = one; w1[2] = one; w1[3] = sbh; w1[4] = sbl;
    w1[5] = zero; w1[6] = zero; w1[7] = zero;
    bf16x8* o = (bf16x8*)(ws + PTX_OFF + (size_t)i * 32);
    o[0] = w0;
    o[1] = w1;
  }
}

// ---------------------------------------------------------------------------
// Phase 2: MFMA pairwise distances + masked row max/min. No LDS, no fences.
// Wave = 32 rows x 512 cols (32 x 16-col steps); explicit register
// double-buffering: 16 groups of 2 steps, next group's 5 loads issued
// before the current group's MFMAs+epilogue consume their data.
// Grid (16 j-chunks, 64 row-blocks) = 1024 blocks = 4/CU, 16 waves/CU.
// ---------------------------------------------------------------------------
__global__ __launch_bounds__(256, 4) void hcl_dist(char* __restrict__ ws) {
  const int lane = threadIdx.x & 63;
  const int wv = threadIdx.x >> 6;
  const int quad = lane >> 4;
  const int n = lane & 15;
  const int i0 = blockIdx.y * 128 + wv * 32;
  const int j0 = blockIdx.x * 512;

  // ---- A side (one-time) ----
  const bf16x8 afeat0 = *(const bf16x8*)(ws + FS2_OFF + (size_t)(i0 + n) * 64 + quad * 16);
  const bf16x8 afeat1 =
      *(const bf16x8*)(ws + FS2_OFF + (size_t)(i0 + 16 + n) * 64 + quad * 16);
  bf16x8 apos0 = {}, apos1 = {};
  if (quad < 2) {  // K slots 0..15 in quads 0,1; quads 2,3 stay zero
    apos0 = *(const bf16x8*)(ws + PSX_OFF + (size_t)(i0 + n) * 32 + quad * 16);
    apos1 = *(const bf16x8*)(ws + PSX_OFF + (size_t)(i0 + 16 + n) * 32 + quad * 16);
  }
  const f32x4 fa0 = *(const f32x4*)(ws + FNS_OFF + (size_t)(i0 + quad * 4) * 4);
  const f32x4 fa1 = *(const f32x4*)(ws + FNS_OFF + (size_t)(i0 + 16 + quad * 4) * 4);

  float maxv[8], minv[8];
#pragma unroll
  for (int r = 0; r < 8; ++r) {
    maxv[r] = -1.0f;
    minv[r] = FLT_MAX;
  }

  const char* pF = ws + FT_OFF + (size_t)(j0 + n) * 64 + quad * 16;
  const char* pP = ws + PTX_OFF + (size_t)(j0 + n) * 32 + quad * 16;
  const float* pN = (const float*)(ws + NT_OFF) + (size_t)blockIdx.x * 512 + n * 32;

  // prime group 0 (steps 0,1)
  bf16x8 cF0 = *(const bf16x8*)(pF);
  bf16x8 cF1 = *(const bf16x8*)(pF + 1024);
  bf16x8 cP0 = *(const bf16x8*)(pP);
  bf16x8 cP1 = *(const bf16x8*)(pP + 512);
  float2 cN = *(const float2*)(pN);

#pragma unroll
  for (int g = 0; g < 16; ++g) {
    bf16x8 nF0, nF1, nP0, nP1;
    float2 nN;
    if (g < 15) {  // prefetch group g+1
      nF0 = *(const bf16x8*)(pF + (2 * g + 2) * 1024);
      nF1 = *(const bf16x8*)(pF + (2 * g + 3) * 1024);
      nP0 = *(const bf16x8*)(pP + (2 * g + 2) * 512);
      nP1 = *(const bf16x8*)(pP + (2 * g + 3) * 512);
      nN = *(const float2*)(pN + 2 * g + 2);
    }

#pragma unroll
    for (int u = 0; u < 2; ++u) {
      const bf16x8 bfeat = u ? cF1 : cF0;
      const bf16x8 bpos = u ? cP1 : cP0;
      const float fb = u ? cN.y : cN.x;

      f32x4 c0, c1, z;
      c0[0] = fa0[0] + fb; c0[1] = fa0[1] + fb; c0[2] = fa0[2] + fb; c0[3] = fa0[3] + fb;
      c1[0] = fa1[0] + fb; c1[1] = fa1[1] + fb; c1[2] = fa1[2] + fb; c1[3] = fa1[3] + fb;
      z[0] = 0.f; z[1] = 0.f; z[2] = 0.f; z[3] = 0.f;

      f32x4 d0 = __builtin_amdgcn_mfma_f32_16x16x32_bf16(afeat0, bfeat, c0, 0, 0, 0);
      f32x4 d1 = __builtin_amdgcn_mfma_f32_16x16x32_bf16(afeat1, bfeat, c1, 0, 0, 0);
      f32x4 u0 = __builtin_amdgcn_mfma_f32_16x16x32_bf16(apos0, bpos, z, 0, 0, 0);
      f32x4 u1 = __builtin_amdgcn_mfma_f32_16x16x32_bf16(apos1, bpos, z, 0, 0, 0);

#pragma unroll
      for (int r = 0; r < 4; ++r) {
        bool p0 = u0[r] < PRC, g0 = u0[r] > NRC;
        maxv[r] = fmaxf(maxv[r], p0 ? d0[r] : -1.0f);
        minv[r] = fminf(minv[r], g0 ? d0[r] : FLT_MAX);
        bool p1 = u1[r] < PRC, g1 = u1[r] > NRC;
        maxv[4 + r] = fmaxf(maxv[4 + r], p1 ? d1[r] : -1.0f);
        minv[4 + r] = fminf(minv[4 + r], g1 ? d1[r] : FLT_MAX);
      }
    }

    if (g < 15) {
      cF0 = nF0; cF1 = nF1; cP0 = nP0; cP1 = nP1; cN = nN;
    }
  }

  // reduce over the 16 col-lanes of each quad, then atomic-merge per row
  unsigned int* maxb = (unsigned int*)(ws + MAXB_OFF);
  unsigned int* minb = (unsigned int*)(ws + MINB_OFF);
#pragma unroll
  for (int r = 0; r < 8; ++r) {
    float mx = maxv[r], mn = minv[r];
#pragma unroll
    for (int sh = 1; sh <= 8; sh <<= 1) {
      mx = fmaxf(mx, __shfl_xor(mx, sh, 64));
      mn = fminf(mn, __shfl_xor(mn, sh, 64));
    }
    if (n == 0) {
      int row = i0 + (r < 4 ? 0 : 16) + quad * 4 + (r & 3);
      atomicMax(maxb + row, __float_as_uint(fmaxf(mx, 0.f)));
      atomicMin(minb + row, __float_as_uint(fmaxf(mn, 0.f)));
    }
  }
}

// ---------------------------------------------------------------------------
// Phase 3: final loss reduction (single block, float4 loads)
// ---------------------------------------------------------------------------
__global__ __launch_bounds__(256) void hcl_loss(const char* __restrict__ ws,
                                               float* __restrict__ out) {
  int t = threadIdx.x;
  const float4* maxb = (const float4*)(ws + MAXB_OFF);
  const float4* minb = (const float4*)(ws + MINB_OFF);
  float sp = 0.f, sn = 0.f;
#pragma unroll
  for (int k = 0; k < 8; ++k) {
    float4 mx = maxb[t + 256 * k];
    float4 mn = minb[t + 256 * k];
    sp += fmaxf(sqrtf(mx.x + EPSF) - POS_TH, 0.f) + fmaxf(sqrtf(mx.y + EPSF) - POS_TH, 0.f) +
          fmaxf(sqrtf(mx.z + EPSF) - POS_TH, 0.f) + fmaxf(sqrtf(mx.w + EPSF) - POS_TH, 0.f);
    sn += fmaxf(NEG_TH - sqrtf(mn.x + EPSF), 0.f) + fmaxf(NEG_TH - sqrtf(mn.y + EPSF), 0.f) +
          fmaxf(NEG_TH - sqrtf(mn.z + EPSF), 0.f) + fmaxf(NEG_TH - sqrtf(mn.w + EPSF), 0.f);
  }
  __shared__ float red[8];
#pragma unroll
  for (int s = 32; s >= 1; s >>= 1) {
    sp += __shfl_down(sp, s, 64);
    sn += __shfl_down(sn, s, 64);
  }
  int wid = t >> 6;
  if ((t & 63) == 0) {
    red[wid] = sp;
    red[4 + wid] = sn;
  }
  __syncthreads();
  if (t == 0) {
    float tsp = red[0] + red[1] + red[2] + red[3];
    float tsn = red[4] + red[5] + red[6] + red[7];
    out[0] = (tsp + tsn) * (1.0f / NN);
  }
}

// ---------------------------------------------------------------------------
extern "C" void kernel_launch(void* const* d_in, const int* in_sizes, int n_in,
                              void* d_out, int out_size, void* d_ws, size_t ws_size,
                              hipStream_t stream) {
  const float* src_pcd = (const float*)d_in[0];
  const float* tgt_pcd = (const float*)d_in[1];
  const float* src_feats = (const float*)d_in[2];
  const float* tgt_feats = (const float*)d_in[3];
  const int* corr = (const int*)d_in[4];
  const float* rot = (const float*)d_in[5];
  const float* trans = (const float*)d_in[6];
  float* out = (float*)d_out;
  char* ws = (char*)d_ws;

  hcl_prep<<<NN * 8 / 256, 256, 0, stream>>>(src_pcd, tgt_pcd, src_feats, tgt_feats, corr,
                                             rot, trans, ws);
  hcl_dist<<<dim3(16, 64), 256, 0, stream>>>(ws);
  hcl_loss<<<1, 256, 0, stream>>>(ws, out);
}

// Round 6
// 178.108 us; speedup vs baseline: 2.3099x; 2.3099x over previous
//
#include <hip/hip_runtime.h>
#include <math.h>
#include <float.h>

#define NN 8192

typedef __bf16 bf16x8 __attribute__((ext_vector_type(8)));
typedef __bf16 bf16x4 __attribute__((ext_vector_type(4)));
typedef float f32x4 __attribute__((ext_vector_type(4)));

constexpr float POS_R2 = 0.0375f * 0.0375f;
constexpr float NEG_R2 = 0.1f * 0.1f;
constexpr float EPSF = 1e-7f;
constexpr float PRC = POS_R2 - EPSF;  // pos:  d2p < PRC
constexpr float NRC = NEG_R2 - EPSF;  // neg:  d2p > NRC
constexpr float POS_TH = 0.1f;
constexpr float NEG_TH = 1.4f;
constexpr float BIG_NEG = -1.0e30f;  // masked-out sentinel for max (fa + this << 0)
constexpr float BIG_POS = 1.0e30f;   // masked-out sentinel for min

// ws byte offsets
#define FT_OFF 0                             // bf16 [NN][32] tgt feats (64 B/row)
#define FS2_OFF (NN * 64)                    // bf16 [NN][32] -2 * src feats
#define PSX_OFF (2 * NN * 64)                // bf16 [NN][16] src pos ext (32 B/row)
#define PTX_OFF (2 * NN * 64 + NN * 32)      // bf16 [NN][16] tgt pos ext
#define PAD_OFF (2 * NN * 64 + 2 * NN * 32)  // 64 B zeros (quad 2/3 over-read)
#define FNS_OFF (PAD_OFF + 64)               // f32 [NN] src feat |.|^2
#define NT4_OFF (FNS_OFF + NN * 4)           // f32 [NN][4] tgt feat |.|^2, broadcast x4
#define MAXB_OFF (NT4_OFF + NN * 16)
#define MINB_OFF (MAXB_OFF + NN * 4)

// ---------------------------------------------------------------------------
// Phase 1: gather + transform + bf16 conversion + MFMA operand packing.
// 8 threads per correspondence; part p handles feat float4 chunk p.
// ---------------------------------------------------------------------------
__global__ __launch_bounds__(256) void hcl_prep(
    const float* __restrict__ src_pcd, const float* __restrict__ tgt_pcd,
    const float* __restrict__ src_feats, const float* __restrict__ tgt_feats,
    const int* __restrict__ corr, const float* __restrict__ rot,
    const float* __restrict__ trans, char* __restrict__ ws) {
  int t = blockIdx.x * 256 + threadIdx.x;  // 0..65535
  int i = t >> 3;
  int p = t & 7;
  int ci = corr[2 * i];
  int cj = corr[2 * i + 1];

  // ---- feats: chunk p (4 dims) ----
  float4 a = ((const float4*)(src_feats + (size_t)ci * 32))[p];
  float4 b = ((const float4*)(tgt_feats + (size_t)cj * 32))[p];
  __bf16 h0 = (__bf16)a.x, h1 = (__bf16)a.y, h2 = (__bf16)a.z, h3 = (__bf16)a.w;
  float f0 = (float)h0, f1 = (float)h1, f2 = (float)h2, f3 = (float)h3;
  float na = f0 * f0 + f1 * f1 + f2 * f2 + f3 * f3;
  bf16x4 osrc;
  osrc[0] = (__bf16)(-2.f * f0); osrc[1] = (__bf16)(-2.f * f1);
  osrc[2] = (__bf16)(-2.f * f2); osrc[3] = (__bf16)(-2.f * f3);
  __bf16 g0 = (__bf16)b.x, g1 = (__bf16)b.y, g2 = (__bf16)b.z, g3 = (__bf16)b.w;
  float e0 = (float)g0, e1 = (float)g1, e2 = (float)g2, e3 = (float)g3;
  float nb = e0 * e0 + e1 * e1 + e2 * e2 + e3 * e3;
  bf16x4 otgt;
  otgt[0] = g0; otgt[1] = g1; otgt[2] = g2; otgt[3] = g3;
  *(bf16x4*)(ws + FS2_OFF + (size_t)i * 64 + p * 8) = osrc;
  *(bf16x4*)(ws + FT_OFF + (size_t)i * 64 + p * 8) = otgt;

  // norm reduce across the 8 parts (adjacent lanes)
  na += __shfl_xor(na, 1, 8);
  na += __shfl_xor(na, 2, 8);
  na += __shfl_xor(na, 4, 8);
  nb += __shfl_xor(nb, 1, 8);
  nb += __shfl_xor(nb, 2, 8);
  nb += __shfl_xor(nb, 4, 8);

  __bf16 one = (__bf16)1.0f, zero = (__bf16)0.0f;

  if (p == 0) {
    ((float*)(ws + FNS_OFF))[i] = na;
    f32x4 nb4 = {nb, nb, nb, nb};  // pre-broadcast: dist kernel C-operand via b128
    ((f32x4*)(ws + NT4_OFF))[i] = nb4;
    ((unsigned int*)(ws + MAXB_OFF))[i] = 0u;           // max sentinel (clamped >= 0)
    ((unsigned int*)(ws + MINB_OFF))[i] = 0x7F7FFFFFu;  // FLT_MAX bits
  } else if (p == 3) {
    if (i == 0) {  // zero the over-read pad after PTX
      f32x4 z = {0.f, 0.f, 0.f, 0.f};
      ((f32x4*)(ws + PAD_OFF))[0] = z;
      ((f32x4*)(ws + PAD_OFF))[1] = z;
      ((f32x4*)(ws + PAD_OFF))[2] = z;
      ((f32x4*)(ws + PAD_OFF))[3] = z;
    }
  } else if (p == 1) {
    // src pos-ext (16 slots): [ah(3), ah(3), al(3), sah, sal, 1, 1, 0,0,0]
    float r00 = rot[0], r01 = rot[1], r02 = rot[2];
    float r10 = rot[3], r11 = rot[4], r12 = rot[5];
    float r20 = rot[6], r21 = rot[7], r22 = rot[8];
    float t0 = trans[0], t1 = trans[1], t2 = trans[2];
    float px = src_pcd[ci * 3 + 0], py = src_pcd[ci * 3 + 1], pz = src_pcd[ci * 3 + 2];
    float qx = r00 * px + r01 * py + r02 * pz + t0;
    float qy = r10 * px + r11 * py + r12 * pz + t1;
    float qz = r20 * px + r21 * py + r22 * pz + t2;
    float sa = qx * qx + qy * qy + qz * qz;
    __bf16 qhx = (__bf16)qx, qhy = (__bf16)qy, qhz = (__bf16)qz;
    __bf16 qlx = (__bf16)(qx - (float)qhx);
    __bf16 qly = (__bf16)(qy - (float)qhy);
    __bf16 qlz = (__bf16)(qz - (float)qhz);
    __bf16 sah = (__bf16)sa;
    __bf16 sal = (__bf16)(sa - (float)sah);
    bf16x8 v0, v1;
    v0[0] = qhx; v0[1] = qhy; v0[2] = qhz; v0[3] = qhx; v0[4] = qhy; v0[5] = qhz;
    v0[6] = qlx; v0[7] = qly;
    v1[0] = qlz; v1[1] = sah; v1[2] = sal; v1[3] = one; v1[4] = one;
    v1[5] = zero; v1[6] = zero; v1[7] = zero;
    bf16x8* o = (bf16x8*)(ws + PSX_OFF + (size_t)i * 32);
    o[0] = v0;
    o[1] = v1;
  } else if (p == 2) {
    // tgt pos-ext (16 slots): [-2bh(3), -2bl(3), -2bh(3), 1, 1, sbh, sbl, 0,0,0]
    float ux = tgt_pcd[cj * 3 + 0], uy = tgt_pcd[cj * 3 + 1], uz = tgt_pcd[cj * 3 + 2];
    float sb = ux * ux + uy * uy + uz * uz;
    __bf16 uhx = (__bf16)ux, uhy = (__bf16)uy, uhz = (__bf16)uz;
    __bf16 ulx = (__bf16)(ux - (float)uhx);
    __bf16 uly = (__bf16)(uy - (float)uhy);
    __bf16 ulz = (__bf16)(uz - (float)uhz);
    __bf16 sbh = (__bf16)sb;
    __bf16 sbl = (__bf16)(sb - (float)sbh);
    __bf16 m2hx = (__bf16)(-2.f * (float)uhx), m2hy = (__bf16)(-2.f * (float)uhy),
           m2hz = (__bf16)(-2.f * (float)uhz);
    __bf16 m2lx = (__bf16)(-2.f * (float)ulx), m2ly = (__bf16)(-2.f * (float)uly),
           m2lz = (__bf16)(-2.f * (float)ulz);
    bf16x8 w0, w1;
    w0[0] = m2hx; w0[1] = m2hy; w0[2] = m2hz; w0[3] = m2lx; w0[4] = m2ly; w0[5] = m2lz;
    w0[6] = m2hx; w0[7] = m2hy;
    w1[0] = m2hz; w1[1] = one; w1[2] = one; w1[3] = sbh; w1[4] = sbl;
    w1[5] = zero; w1[6] = zero; w1[7] = zero;
    bf16x8* o = (bf16x8*)(ws + PTX_OFF + (size_t)i * 32);
    o[0] = w0;
    o[1] = w1;
  }
}

// ---------------------------------------------------------------------------
// Phase 2: MFMA pairwise distances + masked row max/min. No LDS, no fences,
// no register double-buffering (R5's full-unroll prefetch spilled to scratch:
// 452 MB of spill stores -> 335 us. Latency hiding comes from TLP here).
// Wave = 32 rows x 256 cols (16 steps). Grid (32 j-chunks, 64 row-blocks)
// = 2048 blocks = 8 blocks/CU = 8 waves/SIMD (max occupancy, VGPR <= 64).
// Feat MFMA C-operand = tgt-norm broadcast (one b128 load, no v_adds);
// src-norm fa added once after the lane reduction (commutes with max/min).
// ---------------------------------------------------------------------------
__global__ __launch_bounds__(256, 8) void hcl_dist(char* __restrict__ ws) {
  const int lane = threadIdx.x & 63;
  const int wv = threadIdx.x >> 6;
  const int quad = lane >> 4;
  const int n = lane & 15;
  const int i0 = blockIdx.y * 128 + wv * 32;
  const int j0 = blockIdx.x * 256;

  // ---- A side (one-time) ----
  const bf16x8 afeat0 = *(const bf16x8*)(ws + FS2_OFF + (size_t)(i0 + n) * 64 + quad * 16);
  const bf16x8 afeat1 =
      *(const bf16x8*)(ws + FS2_OFF + (size_t)(i0 + 16 + n) * 64 + quad * 16);
  bf16x8 apos0 = {}, apos1 = {};
  if (quad < 2) {  // K slots 0..15 in quads 0,1; quads 2,3 stay zero
    apos0 = *(const bf16x8*)(ws + PSX_OFF + (size_t)(i0 + n) * 32 + quad * 16);
    apos1 = *(const bf16x8*)(ws + PSX_OFF + (size_t)(i0 + 16 + n) * 32 + quad * 16);
  }

  float maxv[8], minv[8];
#pragma unroll
  for (int r = 0; r < 8; ++r) {
    maxv[r] = BIG_NEG;
    minv[r] = BIG_POS;
  }

  const char* pF = ws + FT_OFF + (size_t)(j0 + n) * 64 + quad * 16;
  const char* pP = ws + PTX_OFF + (size_t)(j0 + n) * 32 + quad * 16;
  const char* pN = ws + NT4_OFF + (size_t)(j0 + n) * 16;

#pragma unroll 1  // keep a real loop: bounded hoisting window, no spills
  for (int g = 0; g < 4; ++g) {
#pragma unroll
    for (int u = 0; u < 4; ++u) {
      const bf16x8 bfeat = *(const bf16x8*)(pF + u * 1024);
      const bf16x8 bpos = *(const bf16x8*)(pP + u * 512);
      const f32x4 cb = *(const f32x4*)(pN + u * 256);  // {fb,fb,fb,fb}
      f32x4 z = {0.f, 0.f, 0.f, 0.f};

      // d = fb - 2*dot(feat)  (fa added post-loop); u = d2p via pos-ext rows
      f32x4 d0 = __builtin_amdgcn_mfma_f32_16x16x32_bf16(afeat0, bfeat, cb, 0, 0, 0);
      f32x4 d1 = __builtin_amdgcn_mfma_f32_16x16x32_bf16(afeat1, bfeat, cb, 0, 0, 0);
      f32x4 u0 = __builtin_amdgcn_mfma_f32_16x16x32_bf16(apos0, bpos, z, 0, 0, 0);
      f32x4 u1 = __builtin_amdgcn_mfma_f32_16x16x32_bf16(apos1, bpos, z, 0, 0, 0);

#pragma unroll
      for (int r = 0; r < 4; ++r) {
        maxv[r] = fmaxf(maxv[r], (u0[r] < PRC) ? d0[r] : BIG_NEG);
        minv[r] = fminf(minv[r], (u0[r] > NRC) ? d0[r] : BIG_POS);
        maxv[4 + r] = fmaxf(maxv[4 + r], (u1[r] < PRC) ? d1[r] : BIG_NEG);
        minv[4 + r] = fminf(minv[4 + r], (u1[r] > NRC) ? d1[r] : BIG_POS);
      }
    }
    pF += 4096;
    pP += 2048;
    pN += 1024;
  }

  // ---- reduce over the 16 col-lanes, add row-norm fa, atomic-merge per row ----
  const f32x4 fa0 = *(const f32x4*)(ws + FNS_OFF + (size_t)(i0 + quad * 4) * 4);
  const f32x4 fa1 = *(const f32x4*)(ws + FNS_OFF + (size_t)(i0 + 16 + quad * 4) * 4);
  unsigned int* maxb = (unsigned int*)(ws + MAXB_OFF);
  unsigned int* minb = (unsigned int*)(ws + MINB_OFF);
#pragma unroll
  for (int r = 0; r < 8; ++r) {
    float mx = maxv[r], mn = minv[r];
#pragma unroll
    for (int sh = 1; sh <= 8; sh <<= 1) {
      mx = fmaxf(mx, __shfl_xor(mx, sh, 64));
      mn = fminf(mn, __shfl_xor(mn, sh, 64));
    }
    if (n == 0) {
      float fa = (r < 4) ? fa0[r] : fa1[r - 4];
      int row = i0 + (r < 4 ? 0 : 16) + quad * 4 + (r & 3);
      atomicMax(maxb + row, __float_as_uint(fmaxf(fa + mx, 0.f)));
      atomicMin(minb + row, __float_as_uint(fmaxf(fa + mn, 0.f)));
    }
  }
}

// ---------------------------------------------------------------------------
// Phase 3: final loss reduction (single block, float4 loads)
// ---------------------------------------------------------------------------
__global__ __launch_bounds__(256) void hcl_loss(const char* __restrict__ ws,
                                               float* __restrict__ out) {
  int t = threadIdx.x;
  const float4* maxb = (const float4*)(ws + MAXB_OFF);
  const float4* minb = (const float4*)(ws + MINB_OFF);
  float sp = 0.f, sn = 0.f;
#pragma unroll
  for (int k = 0; k < 8; ++k) {
    float4 mx = maxb[t + 256 * k];
    float4 mn = minb[t + 256 * k];
    sp += fmaxf(sqrtf(mx.x + EPSF) - POS_TH, 0.f) + fmaxf(sqrtf(mx.y + EPSF) - POS_TH, 0.f) +
          fmaxf(sqrtf(mx.z + EPSF) - POS_TH, 0.f) + fmaxf(sqrtf(mx.w + EPSF) - POS_TH, 0.f);
    sn += fmaxf(NEG_TH - sqrtf(mn.x + EPSF), 0.f) + fmaxf(NEG_TH - sqrtf(mn.y + EPSF), 0.f) +
          fmaxf(NEG_TH - sqrtf(mn.z + EPSF), 0.f) + fmaxf(NEG_TH - sqrtf(mn.w + EPSF), 0.f);
  }
  __shared__ float red[8];
#pragma unroll
  for (int s = 32; s >= 1; s >>= 1) {
    sp += __shfl_down(sp, s, 64);
    sn += __shfl_down(sn, s, 64);
  }
  int wid = t >> 6;
  if ((t & 63) == 0) {
    red[wid] = sp;
    red[4 + wid] = sn;
  }
  __syncthreads();
  if (t == 0) {
    float tsp = red[0] + red[1] + red[2] + red[3];
    float tsn = red[4] + red[5] + red[6] + red[7];
    out[0] = (tsp + tsn) * (1.0f / NN);
  }
}

// ---------------------------------------------------------------------------
extern "C" void kernel_launch(void* const* d_in, const int* in_sizes, int n_in,
                              void* d_out, int out_size, void* d_ws, size_t ws_size,
                              hipStream_t stream) {
  const float* src_pcd = (const float*)d_in[0];
  const float* tgt_pcd = (const float*)d_in[1];
  const float* src_feats = (const float*)d_in[2];
  const float* tgt_feats = (const float*)d_in[3];
  const int* corr = (const int*)d_in[4];
  const float* rot = (const float*)d_in[5];
  const float* trans = (const float*)d_in[6];
  float* out = (float*)d_out;
  char* ws = (char*)d_ws;

  hcl_prep<<<NN * 8 / 256, 256, 0, stream>>>(src_pcd, tgt_pcd, src_feats, tgt_feats, corr,
                                             rot, trans, ws);
  hcl_dist<<<dim3(32, 64), 256, 0, stream>>>(ws);
  hcl_loss<<<1, 256, 0, stream>>>(ws, out);
}

// Round 7
// 111.742 us; speedup vs baseline: 3.6818x; 1.5939x over previous
//
#include <hip/hip_runtime.h>
#include <math.h>
#include <float.h>

#define NN 8192

typedef __bf16 bf16x8 __attribute__((ext_vector_type(8)));
typedef __bf16 bf16x4 __attribute__((ext_vector_type(4)));
typedef float f32x4 __attribute__((ext_vector_type(4)));
typedef float f32x16 __attribute__((ext_vector_type(16)));

constexpr float POS_R2 = 0.0375f * 0.0375f;
constexpr float NEG_R2 = 0.1f * 0.1f;
constexpr float EPSF = 1e-7f;
constexpr float PRC = POS_R2 - EPSF;  // pos:  d2p < PRC
constexpr float NRC = NEG_R2 - EPSF;  // neg:  d2p > NRC
constexpr float POS_TH = 0.1f;
constexpr float NEG_TH = 1.4f;
constexpr float BIG_NEG = -1.0e30f;  // masked-out sentinel for max
constexpr float BIG_POS = 1.0e30f;   // masked-out sentinel for min

// ws byte offsets
#define FT_OFF 0                             // bf16 [NN][32] tgt feats (64 B/row)
#define FS2_OFF (NN * 64)                    // bf16 [NN][32] -2 * src feats
#define PSX_OFF (NN * 128)                   // bf16 [NN][16] src pos ext (32 B/row)
#define PTX_OFF (NN * 128 + NN * 32)         // bf16 [NN][16] tgt pos ext
#define PAD_OFF (NN * 192)                   // 64 B zeros (prefetch overrun zone)
#define FNS_OFF (NN * 192 + 64)              // f32 [NN] src feat |.|^2
#define FNT_OFF (FNS_OFF + NN * 4)           // f32 [NN] tgt feat |.|^2
#define MAXB_OFF (FNT_OFF + NN * 4)
#define MINB_OFF (MAXB_OFF + NN * 4)

// ---------------------------------------------------------------------------
// Phase 1: gather + transform + bf16 conversion + MFMA operand packing.
// 8 threads per correspondence; part p handles feat float4 chunk p.
// ---------------------------------------------------------------------------
__global__ __launch_bounds__(256) void hcl_prep(
    const float* __restrict__ src_pcd, const float* __restrict__ tgt_pcd,
    const float* __restrict__ src_feats, const float* __restrict__ tgt_feats,
    const int* __restrict__ corr, const float* __restrict__ rot,
    const float* __restrict__ trans, char* __restrict__ ws) {
  int t = blockIdx.x * 256 + threadIdx.x;  // 0..65535
  int i = t >> 3;
  int p = t & 7;
  int ci = corr[2 * i];
  int cj = corr[2 * i + 1];

  // ---- feats: chunk p (4 dims) ----
  float4 a = ((const float4*)(src_feats + (size_t)ci * 32))[p];
  float4 b = ((const float4*)(tgt_feats + (size_t)cj * 32))[p];
  __bf16 h0 = (__bf16)a.x, h1 = (__bf16)a.y, h2 = (__bf16)a.z, h3 = (__bf16)a.w;
  float f0 = (float)h0, f1 = (float)h1, f2 = (float)h2, f3 = (float)h3;
  float na = f0 * f0 + f1 * f1 + f2 * f2 + f3 * f3;
  bf16x4 osrc;
  osrc[0] = (__bf16)(-2.f * f0); osrc[1] = (__bf16)(-2.f * f1);
  osrc[2] = (__bf16)(-2.f * f2); osrc[3] = (__bf16)(-2.f * f3);
  __bf16 g0 = (__bf16)b.x, g1 = (__bf16)b.y, g2 = (__bf16)b.z, g3 = (__bf16)b.w;
  float e0 = (float)g0, e1 = (float)g1, e2 = (float)g2, e3 = (float)g3;
  float nb = e0 * e0 + e1 * e1 + e2 * e2 + e3 * e3;
  bf16x4 otgt;
  otgt[0] = g0; otgt[1] = g1; otgt[2] = g2; otgt[3] = g3;
  *(bf16x4*)(ws + FS2_OFF + (size_t)i * 64 + p * 8) = osrc;
  *(bf16x4*)(ws + FT_OFF + (size_t)i * 64 + p * 8) = otgt;

  // norm reduce across the 8 parts (adjacent lanes)
  na += __shfl_xor(na, 1, 8);
  na += __shfl_xor(na, 2, 8);
  na += __shfl_xor(na, 4, 8);
  nb += __shfl_xor(nb, 1, 8);
  nb += __shfl_xor(nb, 2, 8);
  nb += __shfl_xor(nb, 4, 8);

  __bf16 one = (__bf16)1.0f, zero = (__bf16)0.0f;

  if (p == 0) {
    ((float*)(ws + FNS_OFF))[i] = na;
    ((float*)(ws + FNT_OFF))[i] = nb;
    ((unsigned int*)(ws + MAXB_OFF))[i] = 0u;           // max sentinel (clamped >= 0)
    ((unsigned int*)(ws + MINB_OFF))[i] = 0x7F7FFFFFu;  // FLT_MAX bits
  } else if (p == 3) {
    if (i == 0) {  // zero the pad after PTX (prefetch-overrun zone)
      f32x4 z = {0.f, 0.f, 0.f, 0.f};
      ((f32x4*)(ws + PAD_OFF))[0] = z;
      ((f32x4*)(ws + PAD_OFF))[1] = z;
      ((f32x4*)(ws + PAD_OFF))[2] = z;
      ((f32x4*)(ws + PAD_OFF))[3] = z;
    }
  } else if (p == 1) {
    // src pos-ext (16 slots): [ah(3), ah(3), al(3), sah, sal, 1, 1, 0,0,0]
    float r00 = rot[0], r01 = rot[1], r02 = rot[2];
    float r10 = rot[3], r11 = rot[4], r12 = rot[5];
    float r20 = rot[6], r21 = rot[7], r22 = rot[8];
    float t0 = trans[0], t1 = trans[1], t2 = trans[2];
    float px = src_pcd[ci * 3 + 0], py = src_pcd[ci * 3 + 1], pz = src_pcd[ci * 3 + 2];
    float qx = r00 * px + r01 * py + r02 * pz + t0;
    float qy = r10 * px + r11 * py + r12 * pz + t1;
    float qz = r20 * px + r21 * py + r22 * pz + t2;
    float sa = qx * qx + qy * qy + qz * qz;
    __bf16 qhx = (__bf16)qx, qhy = (__bf16)qy, qhz = (__bf16)qz;
    __bf16 qlx = (__bf16)(qx - (float)qhx);
    __bf16 qly = (__bf16)(qy - (float)qhy);
    __bf16 qlz = (__bf16)(qz - (float)qhz);
    __bf16 sah = (__bf16)sa;
    __bf16 sal = (__bf16)(sa - (float)sah);
    bf16x8 v0, v1;
    v0[0] = qhx; v0[1] = qhy; v0[2] = qhz; v0[3] = qhx; v0[4] = qhy; v0[5] = qhz;
    v0[6] = qlx; v0[7] = qly;
    v1[0] = qlz; v1[1] = sah; v1[2] = sal; v1[3] = one; v1[4] = one;
    v1[5] = zero; v1[6] = zero; v1[7] = zero;
    bf16x8* o = (bf16x8*)(ws + PSX_OFF + (size_t)i * 32);
    o[0] = v0;
    o[1] = v1;
  } else if (p == 2) {
    // tgt pos-ext (16 slots): [-2bh(3), -2bl(3), -2bh(3), 1, 1, sbh, sbl, 0,0,0]
    float ux = tgt_pcd[cj * 3 + 0], uy = tgt_pcd[cj * 3 + 1], uz = tgt_pcd[cj * 3 + 2];
    float sb = ux * ux + uy * uy + uz * uz;
    __bf16 uhx = (__bf16)ux, uhy = (__bf16)uy, uhz = (__bf16)uz;
    __bf16 ulx = (__bf16)(ux - (float)uhx);
    __bf16 uly = (__bf16)(uy - (float)uhy);
    __bf16 ulz = (__bf16)(uz - (float)uhz);
    __bf16 sbh = (__bf16)sb;
    __bf16 sbl = (__bf16)(sb - (float)sbh);
    __bf16 m2hx = (__bf16)(-2.f * (float)uhx), m2hy = (__bf16)(-2.f * (float)uhy),
           m2hz = (__bf16)(-2.f * (float)uhz);
    __bf16 m2lx = (__bf16)(-2.f * (float)ulx), m2ly = (__bf16)(-2.f * (float)uly),
           m2lz = (__bf16)(-2.f * (float)ulz);
    bf16x8 w0, w1;
    w0[0] = m2hx; w0[1] = m2hy; w0[2] = m2hz; w0[3] = m2lx; w0[4] = m2ly; w0[5] = m2lz;
    w0[6] = m2hx; w0[7] = m2hy;
    w1[0] = m2hz; w1[1] = one; w1[2] = one; w1[3] = sbh; w1[4] = sbl;
    w1[5] = zero; w1[6] = zero; w1[7] = zero;
    bf16x8* o = (bf16x8*)(ws + PTX_OFF + (size_t)i * 32);
    o[0] = w0;
    o[1] = w1;
  }
}

// ---------------------------------------------------------------------------
// Phase 2: MFMA pairwise distances + masked row max/min, 32x32 tiles.
// Wave = 32 rows x 512 cols, 16 steps of 32 cols; per step: 3 MFMAs
// (2x feat K=32, 1x pos K=16) + 4 loads. One-step register prefetch only
// (R5's deep prefetch spilled; R6's (256,8) VGPR cap spilled — here
// (256,4) = 128 VGPRs, ~116 live). Each lane owns ONE column
// (col=lane&31), so tgt-norm fb is a per-lane scalar; src-norm fa is
// added after the lane reduction (commutes with max/min).
// Grid (16 j-chunks, 64 row-blocks) = 1024 blocks = 4 blocks/CU.
// ---------------------------------------------------------------------------
__global__ __launch_bounds__(256, 4) void hcl_dist(char* __restrict__ ws) {
  const int lane = threadIdx.x & 63;
  const int wv = threadIdx.x >> 6;
  const int col = lane & 31;   // A row index m and B col index n
  const int half = lane >> 5;  // k-half selector
  const int i0 = blockIdx.y * 128 + wv * 32;
  const int j0 = blockIdx.x * 512;

  // ---- A side (one-time): A[m=col][k=half*8+j] ----
  const char* aFbase = ws + FS2_OFF + (size_t)(i0 + col) * 64 + half * 16;
  const bf16x8 af1 = *(const bf16x8*)(aFbase);        // k 0..15
  const bf16x8 af2 = *(const bf16x8*)(aFbase + 32);   // k 16..31
  const bf16x8 apos = *(const bf16x8*)(ws + PSX_OFF + (size_t)(i0 + col) * 32 + half * 16);

  float maxv[16], minv[16];
#pragma unroll
  for (int r = 0; r < 16; ++r) {
    maxv[r] = BIG_NEG;
    minv[r] = BIG_POS;
  }

  const char* pF = ws + FT_OFF + (size_t)(j0 + col) * 64 + half * 16;
  const char* pP = ws + PTX_OFF + (size_t)(j0 + col) * 32 + half * 16;
  const char* pN = ws + FNT_OFF + (size_t)(j0 + col) * 4;

  // prime step 0
  bf16x8 cf1 = *(const bf16x8*)(pF);
  bf16x8 cf2 = *(const bf16x8*)(pF + 32);
  bf16x8 cp = *(const bf16x8*)(pP);
  float cfb = *(const float*)(pN);

#pragma unroll 1  // real loop: bounded register window, no spills
  for (int s = 0; s < 16; ++s) {
    // one-step prefetch (last iteration's loads land in scratch regions
    // of ws and are discarded — in-bounds, never consumed)
    bf16x8 nf1 = *(const bf16x8*)(pF + 2048);
    bf16x8 nf2 = *(const bf16x8*)(pF + 2048 + 32);
    bf16x8 np = *(const bf16x8*)(pP + 1024);
    float nfb = *(const float*)(pN + 128);

    f32x16 z = {};
    f32x16 d = __builtin_amdgcn_mfma_f32_32x32x16_bf16(af1, cf1, z, 0, 0, 0);
    d = __builtin_amdgcn_mfma_f32_32x32x16_bf16(af2, cf2, d, 0, 0, 0);
    f32x16 u = __builtin_amdgcn_mfma_f32_32x32x16_bf16(apos, cp, z, 0, 0, 0);

#pragma unroll
    for (int r = 0; r < 16; ++r) {
      float x = d[r] + cfb;  // fb + (-2*dot); fa added post-loop
      maxv[r] = fmaxf(maxv[r], (u[r] < PRC) ? x : BIG_NEG);
      minv[r] = fminf(minv[r], (u[r] > NRC) ? x : BIG_POS);
    }

    cf1 = nf1; cf2 = nf2; cp = np; cfb = nfb;
    pF += 2048;
    pP += 1024;
    pN += 128;
  }

  // ---- reduce over the 32 column-lanes of each half, then atomic-merge ----
  unsigned int* maxb = (unsigned int*)(ws + MAXB_OFF);
  unsigned int* minb = (unsigned int*)(ws + MINB_OFF);
#pragma unroll
  for (int r = 0; r < 16; ++r) {
    float mx = maxv[r], mn = minv[r];
#pragma unroll
    for (int sh = 1; sh <= 16; sh <<= 1) {
      mx = fmaxf(mx, __shfl_xor(mx, sh, 32));
      mn = fminf(mn, __shfl_xor(mn, sh, 32));
    }
    if (col == 0) {
      int row = i0 + (r & 3) + 8 * (r >> 2) + 4 * half;
      float fa = *(const float*)(ws + FNS_OFF + (size_t)row * 4);
      atomicMax(maxb + row, __float_as_uint(fmaxf(fa + mx, 0.f)));
      atomicMin(minb + row, __float_as_uint(fmaxf(fa + mn, 0.f)));
    }
  }
}

// ---------------------------------------------------------------------------
// Phase 3: final loss reduction (single block, float4 loads)
// ---------------------------------------------------------------------------
__global__ __launch_bounds__(256) void hcl_loss(const char* __restrict__ ws,
                                               float* __restrict__ out) {
  int t = threadIdx.x;
  const float4* maxb = (const float4*)(ws + MAXB_OFF);
  const float4* minb = (const float4*)(ws + MINB_OFF);
  float sp = 0.f, sn = 0.f;
#pragma unroll
  for (int k = 0; k < 8; ++k) {
    float4 mx = maxb[t + 256 * k];
    float4 mn = minb[t + 256 * k];
    sp += fmaxf(sqrtf(mx.x + EPSF) - POS_TH, 0.f) + fmaxf(sqrtf(mx.y + EPSF) - POS_TH, 0.f) +
          fmaxf(sqrtf(mx.z + EPSF) - POS_TH, 0.f) + fmaxf(sqrtf(mx.w + EPSF) - POS_TH, 0.f);
    sn += fmaxf(NEG_TH - sqrtf(mn.x + EPSF), 0.f) + fmaxf(NEG_TH - sqrtf(mn.y + EPSF), 0.f) +
          fmaxf(NEG_TH - sqrtf(mn.z + EPSF), 0.f) + fmaxf(NEG_TH - sqrtf(mn.w + EPSF), 0.f);
  }
  __shared__ float red[8];
#pragma unroll
  for (int s = 32; s >= 1; s >>= 1) {
    sp += __shfl_down(sp, s, 64);
    sn += __shfl_down(sn, s, 64);
  }
  int wid = t >> 6;
  if ((t & 63) == 0) {
    red[wid] = sp;
    red[4 + wid] = sn;
  }
  __syncthreads();
  if (t == 0) {
    float tsp = red[0] + red[1] + red[2] + red[3];
    float tsn = red[4] + red[5] + red[6] + red[7];
    out[0] = (tsp + tsn) * (1.0f / NN);
  }
}

// ---------------------------------------------------------------------------
extern "C" void kernel_launch(void* const* d_in, const int* in_sizes, int n_in,
                              void* d_out, int out_size, void* d_ws, size_t ws_size,
                              hipStream_t stream) {
  const float* src_pcd = (const float*)d_in[0];
  const float* tgt_pcd = (const float*)d_in[1];
  const float* src_feats = (const float*)d_in[2];
  const float* tgt_feats = (const float*)d_in[3];
  const int* corr = (const int*)d_in[4];
  const float* rot = (const float*)d_in[5];
  const float* trans = (const float*)d_in[6];
  float* out = (float*)d_out;
  char* ws = (char*)d_ws;

  hcl_prep<<<NN * 8 / 256, 256, 0, stream>>>(src_pcd, tgt_pcd, src_feats, tgt_feats, corr,
                                             rot, trans, ws);
  hcl_dist<<<dim3(16, 64), 256, 0, stream>>>(ws);
  hcl_loss<<<1, 256, 0, stream>>>(ws, out);
}